// Round 11
// baseline (242.471 us; speedup 1.0000x reference)
//
#include <hip/hip_runtime.h>
#include <stdint.h>

// Fused multi-scale ROIAlign (torchvision, aligned=false, sampling_ratio=2).
// R11 = R10 + 2D PATCH path for L2/L3: amortize window rows across py too.
// Bound: L3 bin_h<=0.155 -> 4 py's 3-row windows fit in RC=4 rows (floor
// shift <=1); L2 bin_h<=0.617 -> 2 py fit in RC=4. Thread owns SxQ outputs:
//  L3: 8x4 patch, 4 row-loads/ch-iter for 32 outputs (was 12) - 3x fewer.
//  L2: 4x2 patch, 8 loads/ch-iter for 8 outputs (was 12)      - 1.5x.
// L1 strip / L0 pixel frozen. Trade: L3 patch ~110 VGPR crosses the 64-cliff
// (32->16 waves/CU) - discriminating: win=>instr count rules; lose=>occupancy.

#define C_CH 256
#define CC 32                 // channels per thread
#define NCHUNK (C_CH / CC)

typedef float vfloat4 __attribute__((ext_vector_type(4)));
typedef vfloat4 __attribute__((aligned(4))) vfloat4_u;   // under-aligned 16B load
typedef float vfloat2 __attribute__((ext_vector_type(2)));

struct F2 { float x, y; };    // align-4 8B pair (validated R3/R8)

struct Params {
    const float* feat[4];
    const float* boxes;
    long long outBase[4];     // element offset into out (reference order L0..L3)
    float scale[4];
    int workBase[5];          // cumulative padded work items, kernel order L0,L1,L2,L3
    int M;
};

// ---------------- pixel path (level 0) — paired-tap gathers ----------------
template<int pSh, int hwSh>
__device__ __forceinline__ void pixel_body(
    const float* __restrict__ feat, const float* __restrict__ boxes,
    float* __restrict__ out, int r, int M, float sc)
{
    constexpr int HW = 1 << hwSh, HW2 = HW * HW, K = 1 << (2 * pSh);
    const int pixN = M << (2 * pSh);
    if (r >= pixN * NCHUNK) return;
    const int chunk = r / pixN;
    const int pix = r - chunk * pixN;
    const int m   = pix >> (2 * pSh);
    const int pib = pix & (K - 1);
    const int py  = pib >> pSh;
    const int px  = pib & ((1 << pSh) - 1);

    const float* bxp = boxes + m * 5;
    const int   b   = (int)bxp[0];
    const float rx1 = bxp[1] * sc, ry1 = bxp[2] * sc;
    const float rx2 = bxp[3] * sc, ry2 = bxp[4] * sc;
    const float invP  = 1.0f / (float)(1 << pSh);
    const float bin_w = fmaxf(rx2 - rx1, 1.0f) * invP;
    const float bin_h = fmaxf(ry2 - ry1, 1.0f) * invP;

    int off[8]; float wlo[8], whi[8];
    #pragma unroll
    for (int qy = 0; qy < 2; ++qy) {
        float ys = ry1 + ((float)py + (qy ? 0.75f : 0.25f)) * bin_h;
        bool vy = (ys >= -1.0f) && (ys <= (float)HW);
        float y = fminf(fmaxf(ys, 0.0f), (float)(HW - 1));
        int y0 = (int)y, y1i = min(y0 + 1, HW - 1);
        float ly = y - (float)y0, hy = 1.0f - ly;
        #pragma unroll
        for (int qx = 0; qx < 2; ++qx) {
            float xs = rx1 + ((float)px + (qx ? 0.75f : 0.25f)) * bin_w;
            bool vx = (xs >= -1.0f) && (xs <= (float)HW);
            float x = fminf(fmaxf(xs, 0.0f), (float)(HW - 1));
            int x0 = (int)x;
            float lx = x - (float)x0, hx = 1.0f - lx;
            int xb = min(x0, HW - 2);
            float wx0 = (x0 == xb) ? hx : 0.0f;
            float wx1 = (x0 == xb) ? lx : hx;
            float vw = (vy && vx) ? 0.25f : 0.0f;   // 2x2-sample mean folded in
            int s = (qy * 2 + qx) * 2;
            off[s]     = (y0  << hwSh) + xb;
            wlo[s]     = vw * hy * wx0;  whi[s]     = vw * hy * wx1;
            off[s + 1] = (y1i << hwSh) + xb;
            wlo[s + 1] = vw * ly * wx0;  whi[s + 1] = vw * ly * wx1;
        }
    }

    const float* fb = feat + (size_t)(b * C_CH + chunk * CC) * HW2;
    float* ob = out + (size_t)(m * C_CH + chunk * CC) * K + pib;
    #pragma unroll 2
    for (int c = 0; c < CC; ++c) {
        const float* fc = fb + c * HW2;
        float acc = 0.0f;
        #pragma unroll
        for (int i = 0; i < 8; ++i) {
            F2 v = *(const F2*)(fc + off[i]);
            acc += wlo[i] * v.x + whi[i] * v.y;
        }
        __builtin_nontemporal_store(acc, ob + (size_t)c * K);
    }
}

// ---------------- strip path (level 1) — S px share RC x WC window ----------------
template<int pSh, int hwSh, int S, int WC, int RC>
__device__ __forceinline__ void strip_body(
    const float* __restrict__ feat, const float* __restrict__ boxes,
    float* __restrict__ out, int r, int M, float sc)
{
    constexpr int HW = 1 << hwSh, HW2 = HW * HW, P = 1 << pSh, K = P * P;
    constexpr int NS = K / S;
    static_assert(P / S == 4, "4 strips per row assumed");
    constexpr int lgNS = (NS == 128) ? 7 : (NS == 64 ? 6 : (NS == 32 ? 5 : 0));
    static_assert((1 << lgNS) == NS, "NS pow2");

    const int pixN = M * NS;
    if (r >= pixN * NCHUNK) return;
    const int chunk = r / pixN;
    const int t2    = r - chunk * pixN;
    const int m     = t2 >> lgNS;
    const int strip = t2 & (NS - 1);
    const int py    = strip >> 2;
    const int px0   = (strip & 3) * S;

    const float* bxp = boxes + m * 5;
    const int   b   = (int)bxp[0];
    const float rx1 = bxp[1] * sc, ry1 = bxp[2] * sc;
    const float rx2 = bxp[3] * sc, ry2 = bxp[4] * sc;
    const float invP  = 1.0f / (float)P;
    const float bin_w = fmaxf(rx2 - rx1, 1.0f) * invP;
    const float bin_h = fmaxf(ry2 - ry1, 1.0f) * invP;

    float WY[RC];
    #pragma unroll
    for (int j = 0; j < RC; ++j) WY[j] = 0.0f;
    int rb;
    {
        float ysf = ry1 + ((float)py + 0.25f) * bin_h;
        float yf  = fminf(fmaxf(ysf, 0.0f), (float)(HW - 1));
        rb = min((int)yf, HW - RC);
        #pragma unroll
        for (int qy = 0; qy < 2; ++qy) {
            float ys = ry1 + ((float)py + (qy ? 0.75f : 0.25f)) * bin_h;
            bool vy = (ys >= -1.0f) && (ys <= (float)HW);
            float y = fminf(fmaxf(ys, 0.0f), (float)(HW - 1));
            int y0 = (int)y, y1i = min(y0 + 1, HW - 1);
            float ly = y - (float)y0;
            float w0 = vy ? 0.5f * (1.0f - ly) : 0.0f;
            float w1 = vy ? 0.5f * ly          : 0.0f;
            int s0 = y0 - rb, s1 = y1i - rb;
            #pragma unroll
            for (int j = 0; j < RC; ++j)
                WY[j] += (s0 == j ? w0 : 0.0f) + (s1 == j ? w1 : 0.0f);
        }
    }

    float WX[S][WC];
    int cb;
    {
        float xsf = rx1 + ((float)px0 + 0.25f) * bin_w;
        float xf  = fminf(fmaxf(xsf, 0.0f), (float)(HW - 1));
        cb = min((int)xf, HW - WC);
        #pragma unroll
        for (int s = 0; s < S; ++s) {
            #pragma unroll
            for (int i = 0; i < WC; ++i) WX[s][i] = 0.0f;
            #pragma unroll
            for (int qx = 0; qx < 2; ++qx) {
                float xs = rx1 + ((float)(px0 + s) + (qx ? 0.75f : 0.25f)) * bin_w;
                bool vx = (xs >= -1.0f) && (xs <= (float)HW);
                float x = fminf(fmaxf(xs, 0.0f), (float)(HW - 1));
                int x0 = (int)x, x1i = min(x0 + 1, HW - 1);
                float lx = x - (float)x0;
                float w0 = vx ? 0.5f * (1.0f - lx) : 0.0f;
                float w1 = vx ? 0.5f * lx          : 0.0f;
                int s0 = x0 - cb, s1 = x1i - cb;
                #pragma unroll
                for (int i = 0; i < WC; ++i)
                    WX[s][i] += (s0 == i ? w0 : 0.0f) + (s1 == i ? w1 : 0.0f);
            }
        }
    }

    const float* pf = feat + (size_t)((b * C_CH + chunk * CC) * HW2 + rb * HW + cb);
    float* po = out + (size_t)(((m * C_CH + chunk * CC) << (2 * pSh)) + (py << pSh) + px0);

    #pragma unroll 2
    for (int c = 0; c < CC; ++c) {
        float acc[S];
        #pragma unroll
        for (int s = 0; s < S; ++s) acc[s] = 0.0f;
        #pragma unroll
        for (int j = 0; j < RC; ++j) {
            float f[WC];
            vfloat4 r4 = *(const vfloat4_u*)(pf + j * HW);
            f[0] = r4.x; f[1] = r4.y; f[2] = r4.z; f[3] = r4.w;
            if constexpr (WC == 5) {
                f[4] = pf[j * HW + 4];
            } else if constexpr (WC == 6) {
                F2 t = *(const F2*)(pf + j * HW + 4);
                f[4] = t.x; f[5] = t.y;
            }
            #pragma unroll
            for (int s = 0; s < S; ++s) {
                float rs = 0.0f;
                #pragma unroll
                for (int i = 0; i < WC; ++i) rs += WX[s][i] * f[i];
                acc[s] += WY[j] * rs;
            }
        }
        if constexpr (S == 2) {
            vfloat2 v = {acc[0], acc[1]};
            __builtin_nontemporal_store(v, (vfloat2*)po);
        } else {
            #pragma unroll
            for (int s = 0; s < S; s += 4) {
                vfloat4 v = {acc[s], acc[s+1], acc[s+2], acc[s+3]};
                __builtin_nontemporal_store(v, (vfloat4*)(po + s));
            }
        }
        pf += HW2;
        po += K;
    }
}

// ---------------- 2D patch path (levels 2,3) ----------------
// S px x Q py share one RC-row x WC-col super-window (floor-shift across Q py
// is <=1 because Q*bin_h < 1 at these levels; clamp keeps all taps in [0,RC)).
template<int pSh, int hwSh, int S, int Q, int WC, int RC>
__device__ __forceinline__ void patch_body(
    const float* __restrict__ feat, const float* __restrict__ boxes,
    float* __restrict__ out, int r, int M, float sc)
{
    constexpr int HW = 1 << hwSh, HW2 = HW * HW, P = 1 << pSh, K = P * P;
    constexpr int NP = K / (S * Q);           // patches per (m)
    static_assert(P / S == 4, "4 px-groups per row assumed");
    constexpr int lgNP = (NP == 32) ? 5 : (NP == 64 ? 6 : (NP == 16 ? 4 : 0));
    static_assert((1 << lgNP) == NP, "NP pow2");

    const int pixN = M * NP;
    if (r >= pixN * NCHUNK) return;
    const int chunk = r / pixN;
    const int t2    = r - chunk * pixN;
    const int m     = t2 >> lgNP;
    const int patch = t2 & (NP - 1);
    const int py0   = (patch >> 2) * Q;
    const int px0   = (patch & 3) * S;

    const float* bxp = boxes + m * 5;
    const int   b   = (int)bxp[0];
    const float rx1 = bxp[1] * sc, ry1 = bxp[2] * sc;
    const float rx2 = bxp[3] * sc, ry2 = bxp[4] * sc;
    const float invP  = 1.0f / (float)P;
    const float bin_w = fmaxf(rx2 - rx1, 1.0f) * invP;
    const float bin_h = fmaxf(ry2 - ry1, 1.0f) * invP;

    // Y weights per patch row q, relative to patch base rbP.
    float WYP[Q][RC];
    #pragma unroll
    for (int q = 0; q < Q; ++q)
        #pragma unroll
        for (int j = 0; j < RC; ++j) WYP[q][j] = 0.0f;
    int rbP;
    {
        float ysf = ry1 + ((float)py0 + 0.25f) * bin_h;
        float yf  = fminf(fmaxf(ysf, 0.0f), (float)(HW - 1));
        rbP = min((int)yf, HW - RC);
        #pragma unroll
        for (int q = 0; q < Q; ++q) {
            #pragma unroll
            for (int qy = 0; qy < 2; ++qy) {
                float ys = ry1 + ((float)(py0 + q) + (qy ? 0.75f : 0.25f)) * bin_h;
                bool vy = (ys >= -1.0f) && (ys <= (float)HW);
                float y = fminf(fmaxf(ys, 0.0f), (float)(HW - 1));
                int y0 = (int)y, y1i = min(y0 + 1, HW - 1);
                float ly = y - (float)y0;
                float w0 = vy ? 0.5f * (1.0f - ly) : 0.0f;
                float w1 = vy ? 0.5f * ly          : 0.0f;
                int s0 = y0 - rbP, s1 = y1i - rbP;   // in [0,RC) by bin_h bound
                #pragma unroll
                for (int j = 0; j < RC; ++j)
                    WYP[q][j] += (s0 == j ? w0 : 0.0f) + (s1 == j ? w1 : 0.0f);
            }
        }
    }

    // X weights per strip pixel (same as strip path).
    float WX[S][WC];
    int cb;
    {
        float xsf = rx1 + ((float)px0 + 0.25f) * bin_w;
        float xf  = fminf(fmaxf(xsf, 0.0f), (float)(HW - 1));
        cb = min((int)xf, HW - WC);
        #pragma unroll
        for (int s = 0; s < S; ++s) {
            #pragma unroll
            for (int i = 0; i < WC; ++i) WX[s][i] = 0.0f;
            #pragma unroll
            for (int qx = 0; qx < 2; ++qx) {
                float xs = rx1 + ((float)(px0 + s) + (qx ? 0.75f : 0.25f)) * bin_w;
                bool vx = (xs >= -1.0f) && (xs <= (float)HW);
                float x = fminf(fmaxf(xs, 0.0f), (float)(HW - 1));
                int x0 = (int)x, x1i = min(x0 + 1, HW - 1);
                float lx = x - (float)x0;
                float w0 = vx ? 0.5f * (1.0f - lx) : 0.0f;
                float w1 = vx ? 0.5f * lx          : 0.0f;
                int s0 = x0 - cb, s1 = x1i - cb;
                #pragma unroll
                for (int i = 0; i < WC; ++i)
                    WX[s][i] += (s0 == i ? w0 : 0.0f) + (s1 == i ? w1 : 0.0f);
            }
        }
    }

    const float* pf = feat + (size_t)((b * C_CH + chunk * CC) * HW2 + rbP * HW + cb);
    float* po = out + (size_t)(((m * C_CH + chunk * CC) << (2 * pSh)) + (py0 << pSh) + px0);

    #pragma unroll 2
    for (int c = 0; c < CC; ++c) {
        float acc[Q][S];
        #pragma unroll
        for (int q = 0; q < Q; ++q)
            #pragma unroll
            for (int s = 0; s < S; ++s) acc[q][s] = 0.0f;

        // Row-streaming over the shared RC-row window.
        #pragma unroll
        for (int j = 0; j < RC; ++j) {
            float f[WC];
            vfloat4 r4 = *(const vfloat4_u*)(pf + j * HW);
            f[0] = r4.x; f[1] = r4.y; f[2] = r4.z; f[3] = r4.w;
            if constexpr (WC == 5) f[4] = pf[j * HW + 4];
            float rs[S];
            #pragma unroll
            for (int s = 0; s < S; ++s) {
                float v = 0.0f;
                #pragma unroll
                for (int i = 0; i < WC; ++i) v += WX[s][i] * f[i];
                rs[s] = v;
            }
            #pragma unroll
            for (int q = 0; q < Q; ++q) {
                float wy = WYP[q][j];
                #pragma unroll
                for (int s = 0; s < S; ++s) acc[q][s] += wy * rs[s];
            }
        }

        #pragma unroll
        for (int q = 0; q < Q; ++q) {
            float* pr = po + (q << pSh);
            #pragma unroll
            for (int s = 0; s < S; s += 4) {       // px0 mult of 4 -> 16B aligned
                vfloat4 v = {acc[q][s], acc[q][s+1], acc[q][s+2], acc[q][s+3]};
                __builtin_nontemporal_store(v, (vfloat4*)(pr + s));
            }
        }
        pf += HW2;
        po += K;
    }
}

__global__ __launch_bounds__(256, 4) void msroi_kernel(Params p, float* __restrict__ out)
{
    const int blockStart = blockIdx.x * 256;      // blocks never straddle levels
    const int lvl = (blockStart >= p.workBase[1])
                  + (blockStart >= p.workBase[2])
                  + (blockStart >= p.workBase[3]);
    const int r = blockStart + (int)threadIdx.x - p.workBase[lvl];
    // kernel work order (heavy-first): 0->L0 pixels, 1->L1 strips(S=2),
    //                                  2->L2 patches(4x2), 3->L3 patches(8x4)
    if (lvl == 0)
        pixel_body<2, 7>(p.feat[0], p.boxes, out + p.outBase[0], r, p.M, p.scale[0]);
    else if (lvl == 1)
        strip_body<3, 6, 2, 6, 4>(p.feat[1], p.boxes, out + p.outBase[1], r, p.M, p.scale[1]);
    else if (lvl == 2)
        patch_body<4, 5, 4, 2, 5, 4>(p.feat[2], p.boxes, out + p.outBase[2], r, p.M, p.scale[2]);
    else
        patch_body<5, 4, 8, 4, 4, 4>(p.feat[3], p.boxes, out + p.outBase[3], r, p.M, p.scale[3]);
}

extern "C" void kernel_launch(void* const* d_in, const int* in_sizes, int n_in,
                              void* d_out, int out_size, void* d_ws, size_t ws_size,
                              hipStream_t stream) {
    const int M = in_sizes[4] / 5;

    Params p;
    p.feat[0] = (const float*)d_in[0];  // [2,256,128,128]
    p.feat[1] = (const float*)d_in[1];  // [2,256,64,64]
    p.feat[2] = (const float*)d_in[2];  // [2,256,32,32]
    p.feat[3] = (const float*)d_in[3];  // [2,256,16,16]
    p.boxes   = (const float*)d_in[4];
    p.M = M;
    const float scales[4] = {0.125f, 0.0625f, 0.03125f, 0.015625f};
    for (int l = 0; l < 4; ++l) p.scale[l] = scales[l];

    // Output bases in reference return order (L0..L3).
    p.outBase[0] = 0;
    p.outBase[1] = p.outBase[0] + (long long)M * C_CH * 4 * 4;
    p.outBase[2] = p.outBase[1] + (long long)M * C_CH * 8 * 8;
    p.outBase[3] = p.outBase[2] + (long long)M * C_CH * 16 * 16;

    // Work sizes, kernel order L0 pixels, L1 strips(2), L2 patches(4x2),
    // L3 patches(8x4).
    const int work[4] = {
        M * NCHUNK * (4 * 4),             // L0 pixels
        M * NCHUNK * (8 * 8 / 2),         // L1 strips
        M * NCHUNK * (16 * 16 / (4 * 2)), // L2 patches
        M * NCHUNK * (32 * 32 / (8 * 4))  // L3 patches
    };
    p.workBase[0] = 0;
    for (int i = 0; i < 4; ++i)
        p.workBase[i + 1] = p.workBase[i] + ((work[i] + 255) & ~255);

    const int blocks = p.workBase[4] / 256;
    msroi_kernel<<<blocks, 256, 0, stream>>>(p, (float*)d_out);
}

// Round 12
// 111.995 us; speedup vs baseline: 2.1650x; 2.1650x over previous
//
#include <hip/hip_runtime.h>
#include <stdint.h>

// Fused multi-scale ROIAlign (torchvision, aligned=false, sampling_ratio=2).
// R12 = R10 (best, 186.6us) + L3 strip S=8 -> S=4.
// R11 post-mortem found WRITE_SIZE = 613 MB vs logical 408 MB: the L3 path's
// two half-density float4 NT stores per lane (16B written / 16B gap per instr)
// defeat sector combining -> L3's 315 MB streams out ~2x. With S=4 each lane
// issues ONE float4 store and lanes 0-7 cover a full 128B line contiguously.
// Bonus: L3 threads double (307K -> 614K) for finer drain granularity.
// R11's patch path is reverted entirely (work collapse -> 15.6% occupancy).
// Frozen from R10: pixel L0 (paired 8B gathers), strip L1 (S=2, 1x8B store),
// strip L2 (S=4, 1x16B store), heavy-first order, launch_bounds(256,4), NT.

#define C_CH 256
#define CC 32                 // channels per thread
#define NCHUNK (C_CH / CC)

typedef float vfloat4 __attribute__((ext_vector_type(4)));
typedef vfloat4 __attribute__((aligned(4))) vfloat4_u;   // under-aligned 16B load
typedef float vfloat2 __attribute__((ext_vector_type(2)));

struct F2 { float x, y; };    // align-4 8B pair (validated R3/R8)

struct Params {
    const float* feat[4];
    const float* boxes;
    long long outBase[4];     // element offset into out (reference order L0..L3)
    float scale[4];
    int workBase[5];          // cumulative padded work items, kernel order L0,L1,L2,L3
    int M;
};

// ---------------- pixel path (level 0) — paired-tap gathers ----------------
template<int pSh, int hwSh>
__device__ __forceinline__ void pixel_body(
    const float* __restrict__ feat, const float* __restrict__ boxes,
    float* __restrict__ out, int r, int M, float sc)
{
    constexpr int HW = 1 << hwSh, HW2 = HW * HW, K = 1 << (2 * pSh);
    const int pixN = M << (2 * pSh);
    if (r >= pixN * NCHUNK) return;
    const int chunk = r / pixN;
    const int pix = r - chunk * pixN;
    const int m   = pix >> (2 * pSh);
    const int pib = pix & (K - 1);
    const int py  = pib >> pSh;
    const int px  = pib & ((1 << pSh) - 1);

    const float* bxp = boxes + m * 5;
    const int   b   = (int)bxp[0];
    const float rx1 = bxp[1] * sc, ry1 = bxp[2] * sc;
    const float rx2 = bxp[3] * sc, ry2 = bxp[4] * sc;
    const float invP  = 1.0f / (float)(1 << pSh);
    const float bin_w = fmaxf(rx2 - rx1, 1.0f) * invP;
    const float bin_h = fmaxf(ry2 - ry1, 1.0f) * invP;

    int off[8]; float wlo[8], whi[8];
    #pragma unroll
    for (int qy = 0; qy < 2; ++qy) {
        float ys = ry1 + ((float)py + (qy ? 0.75f : 0.25f)) * bin_h;
        bool vy = (ys >= -1.0f) && (ys <= (float)HW);
        float y = fminf(fmaxf(ys, 0.0f), (float)(HW - 1));
        int y0 = (int)y, y1i = min(y0 + 1, HW - 1);
        float ly = y - (float)y0, hy = 1.0f - ly;
        #pragma unroll
        for (int qx = 0; qx < 2; ++qx) {
            float xs = rx1 + ((float)px + (qx ? 0.75f : 0.25f)) * bin_w;
            bool vx = (xs >= -1.0f) && (xs <= (float)HW);
            float x = fminf(fmaxf(xs, 0.0f), (float)(HW - 1));
            int x0 = (int)x;
            float lx = x - (float)x0, hx = 1.0f - lx;
            int xb = min(x0, HW - 2);
            float wx0 = (x0 == xb) ? hx : 0.0f;
            float wx1 = (x0 == xb) ? lx : hx;
            float vw = (vy && vx) ? 0.25f : 0.0f;   // 2x2-sample mean folded in
            int s = (qy * 2 + qx) * 2;
            off[s]     = (y0  << hwSh) + xb;
            wlo[s]     = vw * hy * wx0;  whi[s]     = vw * hy * wx1;
            off[s + 1] = (y1i << hwSh) + xb;
            wlo[s + 1] = vw * ly * wx0;  whi[s + 1] = vw * ly * wx1;
        }
    }

    const float* fb = feat + (size_t)(b * C_CH + chunk * CC) * HW2;
    float* ob = out + (size_t)(m * C_CH + chunk * CC) * K + pib;
    #pragma unroll 2
    for (int c = 0; c < CC; ++c) {
        const float* fc = fb + c * HW2;
        float acc = 0.0f;
        #pragma unroll
        for (int i = 0; i < 8; ++i) {
            F2 v = *(const F2*)(fc + off[i]);
            acc += wlo[i] * v.x + whi[i] * v.y;
        }
        __builtin_nontemporal_store(acc, ob + (size_t)c * K);
    }
}

// ---------------- strip-separable path (levels 1,2,3) ----------------
// S consecutive x-pixels (same py) share an RC-row x WC-col feature window.
// GX = P/S strips per output row; px0 = (strip % GX) * S.
template<int pSh, int hwSh, int S, int WC, int RC>
__device__ __forceinline__ void strip_body(
    const float* __restrict__ feat, const float* __restrict__ boxes,
    float* __restrict__ out, int r, int M, float sc)
{
    constexpr int HW = 1 << hwSh, HW2 = HW * HW, P = 1 << pSh, K = P * P;
    constexpr int NS = K / S;                 // strips per (m)
    constexpr int GX = P / S;                 // strips per output row
    static_assert(GX == 4 || GX == 8, "4 or 8 strips per row");
    constexpr int lgGX = (GX == 8) ? 3 : 2;
    static_assert(WC >= 4 && WC <= 6, "window 4..6 cols");
    constexpr int lgNS = (NS == 256) ? 8 : (NS == 128) ? 7 :
                         (NS == 64) ? 6 : (NS == 32 ? 5 : 0);
    static_assert((1 << lgNS) == NS, "NS pow2");

    const int pixN = M * NS;
    if (r >= pixN * NCHUNK) return;
    const int chunk = r / pixN;
    const int t2    = r - chunk * pixN;
    const int m     = t2 >> lgNS;
    const int strip = t2 & (NS - 1);
    const int py    = strip >> lgGX;
    const int px0   = (strip & (GX - 1)) * S;

    const float* bxp = boxes + m * 5;
    const int   b   = (int)bxp[0];
    const float rx1 = bxp[1] * sc, ry1 = bxp[2] * sc;
    const float rx2 = bxp[3] * sc, ry2 = bxp[4] * sc;
    const float invP  = 1.0f / (float)P;
    const float bin_w = fmaxf(rx2 - rx1, 1.0f) * invP;
    const float bin_h = fmaxf(ry2 - ry1, 1.0f) * invP;

    // Y weights (shared across the strip): RC-row window starting at rb.
    float WY[RC];
    #pragma unroll
    for (int j = 0; j < RC; ++j) WY[j] = 0.0f;
    int rb;
    {
        float ysf = ry1 + ((float)py + 0.25f) * bin_h;
        float yf  = fminf(fmaxf(ysf, 0.0f), (float)(HW - 1));
        rb = min((int)yf, HW - RC);
        #pragma unroll
        for (int qy = 0; qy < 2; ++qy) {
            float ys = ry1 + ((float)py + (qy ? 0.75f : 0.25f)) * bin_h;
            bool vy = (ys >= -1.0f) && (ys <= (float)HW);
            float y = fminf(fmaxf(ys, 0.0f), (float)(HW - 1));
            int y0 = (int)y, y1i = min(y0 + 1, HW - 1);
            float ly = y - (float)y0;
            float w0 = vy ? 0.5f * (1.0f - ly) : 0.0f;   // 0.5 = mean over 2 qy
            float w1 = vy ? 0.5f * ly          : 0.0f;
            int s0 = y0 - rb, s1 = y1i - rb;
            #pragma unroll
            for (int j = 0; j < RC; ++j)
                WY[j] += (s0 == j ? w0 : 0.0f) + (s1 == j ? w1 : 0.0f);
        }
    }

    // X weights per strip pixel: WC-col window starting at cb.
    float WX[S][WC];
    int cb;
    {
        float xsf = rx1 + ((float)px0 + 0.25f) * bin_w;
        float xf  = fminf(fmaxf(xsf, 0.0f), (float)(HW - 1));
        cb = min((int)xf, HW - WC);
        #pragma unroll
        for (int s = 0; s < S; ++s) {
            #pragma unroll
            for (int i = 0; i < WC; ++i) WX[s][i] = 0.0f;
            #pragma unroll
            for (int qx = 0; qx < 2; ++qx) {
                float xs = rx1 + ((float)(px0 + s) + (qx ? 0.75f : 0.25f)) * bin_w;
                bool vx = (xs >= -1.0f) && (xs <= (float)HW);
                float x = fminf(fmaxf(xs, 0.0f), (float)(HW - 1));
                int x0 = (int)x, x1i = min(x0 + 1, HW - 1);
                float lx = x - (float)x0;
                float w0 = vx ? 0.5f * (1.0f - lx) : 0.0f; // 0.5 = mean over 2 qx
                float w1 = vx ? 0.5f * lx          : 0.0f;
                int s0 = x0 - cb, s1 = x1i - cb;
                #pragma unroll
                for (int i = 0; i < WC; ++i)
                    WX[s][i] += (s0 == i ? w0 : 0.0f) + (s1 == i ? w1 : 0.0f);
            }
        }
    }

    const float* pf = feat + (size_t)((b * C_CH + chunk * CC) * HW2 + rb * HW + cb);
    float* po = out + (size_t)(((m * C_CH + chunk * CC) << (2 * pSh)) + (py << pSh) + px0);

    #pragma unroll 2
    for (int c = 0; c < CC; ++c) {
        float acc[S];
        #pragma unroll
        for (int s = 0; s < S; ++s) acc[s] = 0.0f;

        // Row-streaming: load one row (vectorized), accumulate, discard.
        #pragma unroll
        for (int j = 0; j < RC; ++j) {
            float f[WC];
            vfloat4 r4 = *(const vfloat4_u*)(pf + j * HW);
            f[0] = r4.x; f[1] = r4.y; f[2] = r4.z; f[3] = r4.w;
            if constexpr (WC == 5) {
                f[4] = pf[j * HW + 4];
            } else if constexpr (WC == 6) {
                F2 t = *(const F2*)(pf + j * HW + 4);
                f[4] = t.x; f[5] = t.y;
            }
            #pragma unroll
            for (int s = 0; s < S; ++s) {
                float rs = 0.0f;
                #pragma unroll
                for (int i = 0; i < WC; ++i) rs += WX[s][i] * f[i];
                acc[s] += WY[j] * rs;
            }
        }

        if constexpr (S == 2) {                    // px0 even -> 8B aligned
            vfloat2 v = {acc[0], acc[1]};
            __builtin_nontemporal_store(v, (vfloat2*)po);
        } else {
            #pragma unroll
            for (int s = 0; s < S; s += 4) {       // px0 mult of 4 -> 16B aligned
                vfloat4 v = {acc[s], acc[s+1], acc[s+2], acc[s+3]};
                __builtin_nontemporal_store(v, (vfloat4*)(po + s));
            }
        }
        pf += HW2;
        po += K;
    }
}

__global__ __launch_bounds__(256, 4) void msroi_kernel(Params p, float* __restrict__ out)
{
    const int blockStart = blockIdx.x * 256;      // blocks never straddle levels
    const int lvl = (blockStart >= p.workBase[1])
                  + (blockStart >= p.workBase[2])
                  + (blockStart >= p.workBase[3]);
    const int r = blockStart + (int)threadIdx.x - p.workBase[lvl];
    // kernel work order (heavy-first): 0->L0 pixels, 1->L1 strips(S=2),
    //                                  2->L2 strips(S=4), 3->L3 strips(S=4)
    if (lvl == 0)
        pixel_body<2, 7>(p.feat[0], p.boxes, out + p.outBase[0], r, p.M, p.scale[0]);
    else if (lvl == 1)
        strip_body<3, 6, 2, 6, 4>(p.feat[1], p.boxes, out + p.outBase[1], r, p.M, p.scale[1]);
    else if (lvl == 2)
        strip_body<4, 5, 4, 5, 3>(p.feat[2], p.boxes, out + p.outBase[2], r, p.M, p.scale[2]);
    else
        strip_body<5, 4, 4, 4, 3>(p.feat[3], p.boxes, out + p.outBase[3], r, p.M, p.scale[3]);
}

extern "C" void kernel_launch(void* const* d_in, const int* in_sizes, int n_in,
                              void* d_out, int out_size, void* d_ws, size_t ws_size,
                              hipStream_t stream) {
    const int M = in_sizes[4] / 5;

    Params p;
    p.feat[0] = (const float*)d_in[0];  // [2,256,128,128]
    p.feat[1] = (const float*)d_in[1];  // [2,256,64,64]
    p.feat[2] = (const float*)d_in[2];  // [2,256,32,32]
    p.feat[3] = (const float*)d_in[3];  // [2,256,16,16]
    p.boxes   = (const float*)d_in[4];
    p.M = M;
    const float scales[4] = {0.125f, 0.0625f, 0.03125f, 0.015625f};
    for (int l = 0; l < 4; ++l) p.scale[l] = scales[l];

    // Output bases in reference return order (L0..L3).
    p.outBase[0] = 0;
    p.outBase[1] = p.outBase[0] + (long long)M * C_CH * 4 * 4;
    p.outBase[2] = p.outBase[1] + (long long)M * C_CH * 8 * 8;
    p.outBase[3] = p.outBase[2] + (long long)M * C_CH * 16 * 16;

    // Work sizes, kernel order L0 pixels, L1 strips(2), L2 strips(4), L3 strips(4).
    const int work[4] = {
        M * NCHUNK * (4 * 4),         // L0 pixels
        M * NCHUNK * (8 * 8 / 2),     // L1 strips
        M * NCHUNK * (16 * 16 / 4),   // L2 strips
        M * NCHUNK * (32 * 32 / 4)    // L3 strips (S=4, fully coalesced stores)
    };
    p.workBase[0] = 0;
    for (int i = 0; i < 4; ++i)
        p.workBase[i + 1] = p.workBase[i] + ((work[i] + 255) & ~255);

    const int blocks = p.workBase[4] / 256;
    msroi_kernel<<<blocks, 256, 0, stream>>>(p, (float*)d_out);
}

// Round 13
// 111.543 us; speedup vs baseline: 2.1738x; 1.0041x over previous
//
#include <hip/hip_runtime.h>
#include <stdint.h>

// Fused multi-scale ROIAlign (torchvision, aligned=false, sampling_ratio=2).
// R13 = R12 (111.9us) + per-level channel-chunk granularity for packing:
//   L0 CC=8 (150->600 blocks), L1 CC=16 (300->600), L2 CC=16 (600->1200),
//   L3 CC=16 (2400->4800). 7200 blocks ~= 28/CU. Line visits and store
//   traffic are CC-invariant (chunks touch disjoint channels); only the
//   per-thread coord setup repeats more (VALU has huge headroom).
// Frozen from R12: S=4 L3 strips (full-density wave-contiguous NT stores -
//   the R12 lesson: NT stores bypass L2 so every store instr must be
//   full-density; gaps double HBM write sectors), pixel L0 paired 8B gathers,
//   strip L1 S=2 / L2 S=4, heavy-first order, launch_bounds(256,4), VGPR<=64.

#define C_CH 256

typedef float vfloat4 __attribute__((ext_vector_type(4)));
typedef vfloat4 __attribute__((aligned(4))) vfloat4_u;   // under-aligned 16B load
typedef float vfloat2 __attribute__((ext_vector_type(2)));

struct F2 { float x, y; };    // align-4 8B pair (validated R3/R8)

struct Params {
    const float* feat[4];
    const float* boxes;
    long long outBase[4];     // element offset into out (reference order L0..L3)
    float scale[4];
    int workBase[5];          // cumulative padded work items, kernel order L0,L1,L2,L3
    int M;
};

// ---------------- pixel path (level 0) — paired-tap gathers ----------------
template<int pSh, int hwSh, int CC>
__device__ __forceinline__ void pixel_body(
    const float* __restrict__ feat, const float* __restrict__ boxes,
    float* __restrict__ out, int r, int M, float sc)
{
    constexpr int HW = 1 << hwSh, HW2 = HW * HW, K = 1 << (2 * pSh);
    constexpr int NCHUNK = C_CH / CC;
    const int pixN = M << (2 * pSh);
    if (r >= pixN * NCHUNK) return;
    const int chunk = r / pixN;
    const int pix = r - chunk * pixN;
    const int m   = pix >> (2 * pSh);
    const int pib = pix & (K - 1);
    const int py  = pib >> pSh;
    const int px  = pib & ((1 << pSh) - 1);

    const float* bxp = boxes + m * 5;
    const int   b   = (int)bxp[0];
    const float rx1 = bxp[1] * sc, ry1 = bxp[2] * sc;
    const float rx2 = bxp[3] * sc, ry2 = bxp[4] * sc;
    const float invP  = 1.0f / (float)(1 << pSh);
    const float bin_w = fmaxf(rx2 - rx1, 1.0f) * invP;
    const float bin_h = fmaxf(ry2 - ry1, 1.0f) * invP;

    int off[8]; float wlo[8], whi[8];
    #pragma unroll
    for (int qy = 0; qy < 2; ++qy) {
        float ys = ry1 + ((float)py + (qy ? 0.75f : 0.25f)) * bin_h;
        bool vy = (ys >= -1.0f) && (ys <= (float)HW);
        float y = fminf(fmaxf(ys, 0.0f), (float)(HW - 1));
        int y0 = (int)y, y1i = min(y0 + 1, HW - 1);
        float ly = y - (float)y0, hy = 1.0f - ly;
        #pragma unroll
        for (int qx = 0; qx < 2; ++qx) {
            float xs = rx1 + ((float)px + (qx ? 0.75f : 0.25f)) * bin_w;
            bool vx = (xs >= -1.0f) && (xs <= (float)HW);
            float x = fminf(fmaxf(xs, 0.0f), (float)(HW - 1));
            int x0 = (int)x;
            float lx = x - (float)x0, hx = 1.0f - lx;
            int xb = min(x0, HW - 2);
            float wx0 = (x0 == xb) ? hx : 0.0f;
            float wx1 = (x0 == xb) ? lx : hx;
            float vw = (vy && vx) ? 0.25f : 0.0f;   // 2x2-sample mean folded in
            int s = (qy * 2 + qx) * 2;
            off[s]     = (y0  << hwSh) + xb;
            wlo[s]     = vw * hy * wx0;  whi[s]     = vw * hy * wx1;
            off[s + 1] = (y1i << hwSh) + xb;
            wlo[s + 1] = vw * ly * wx0;  whi[s + 1] = vw * ly * wx1;
        }
    }

    const float* fb = feat + (size_t)(b * C_CH + chunk * CC) * HW2;
    float* ob = out + (size_t)(m * C_CH + chunk * CC) * K + pib;
    #pragma unroll 2
    for (int c = 0; c < CC; ++c) {
        const float* fc = fb + c * HW2;
        float acc = 0.0f;
        #pragma unroll
        for (int i = 0; i < 8; ++i) {
            F2 v = *(const F2*)(fc + off[i]);
            acc += wlo[i] * v.x + whi[i] * v.y;
        }
        __builtin_nontemporal_store(acc, ob + (size_t)c * K);
    }
}

// ---------------- strip-separable path (levels 1,2,3) ----------------
// S consecutive x-pixels (same py) share an RC-row x WC-col feature window.
template<int pSh, int hwSh, int S, int WC, int RC, int CC>
__device__ __forceinline__ void strip_body(
    const float* __restrict__ feat, const float* __restrict__ boxes,
    float* __restrict__ out, int r, int M, float sc)
{
    constexpr int HW = 1 << hwSh, HW2 = HW * HW, P = 1 << pSh, K = P * P;
    constexpr int NCHUNK = C_CH / CC;
    constexpr int NS = K / S;                 // strips per (m)
    constexpr int GX = P / S;                 // strips per output row
    static_assert(GX == 4 || GX == 8, "4 or 8 strips per row");
    constexpr int lgGX = (GX == 8) ? 3 : 2;
    static_assert(WC >= 4 && WC <= 6, "window 4..6 cols");
    constexpr int lgNS = (NS == 256) ? 8 : (NS == 128) ? 7 :
                         (NS == 64) ? 6 : (NS == 32 ? 5 : 0);
    static_assert((1 << lgNS) == NS, "NS pow2");

    const int pixN = M * NS;
    if (r >= pixN * NCHUNK) return;
    const int chunk = r / pixN;
    const int t2    = r - chunk * pixN;
    const int m     = t2 >> lgNS;
    const int strip = t2 & (NS - 1);
    const int py    = strip >> lgGX;
    const int px0   = (strip & (GX - 1)) * S;

    const float* bxp = boxes + m * 5;
    const int   b   = (int)bxp[0];
    const float rx1 = bxp[1] * sc, ry1 = bxp[2] * sc;
    const float rx2 = bxp[3] * sc, ry2 = bxp[4] * sc;
    const float invP  = 1.0f / (float)P;
    const float bin_w = fmaxf(rx2 - rx1, 1.0f) * invP;
    const float bin_h = fmaxf(ry2 - ry1, 1.0f) * invP;

    // Y weights (shared across the strip): RC-row window starting at rb.
    float WY[RC];
    #pragma unroll
    for (int j = 0; j < RC; ++j) WY[j] = 0.0f;
    int rb;
    {
        float ysf = ry1 + ((float)py + 0.25f) * bin_h;
        float yf  = fminf(fmaxf(ysf, 0.0f), (float)(HW - 1));
        rb = min((int)yf, HW - RC);
        #pragma unroll
        for (int qy = 0; qy < 2; ++qy) {
            float ys = ry1 + ((float)py + (qy ? 0.75f : 0.25f)) * bin_h;
            bool vy = (ys >= -1.0f) && (ys <= (float)HW);
            float y = fminf(fmaxf(ys, 0.0f), (float)(HW - 1));
            int y0 = (int)y, y1i = min(y0 + 1, HW - 1);
            float ly = y - (float)y0;
            float w0 = vy ? 0.5f * (1.0f - ly) : 0.0f;   // 0.5 = mean over 2 qy
            float w1 = vy ? 0.5f * ly          : 0.0f;
            int s0 = y0 - rb, s1 = y1i - rb;
            #pragma unroll
            for (int j = 0; j < RC; ++j)
                WY[j] += (s0 == j ? w0 : 0.0f) + (s1 == j ? w1 : 0.0f);
        }
    }

    // X weights per strip pixel: WC-col window starting at cb.
    float WX[S][WC];
    int cb;
    {
        float xsf = rx1 + ((float)px0 + 0.25f) * bin_w;
        float xf  = fminf(fmaxf(xsf, 0.0f), (float)(HW - 1));
        cb = min((int)xf, HW - WC);
        #pragma unroll
        for (int s = 0; s < S; ++s) {
            #pragma unroll
            for (int i = 0; i < WC; ++i) WX[s][i] = 0.0f;
            #pragma unroll
            for (int qx = 0; qx < 2; ++qx) {
                float xs = rx1 + ((float)(px0 + s) + (qx ? 0.75f : 0.25f)) * bin_w;
                bool vx = (xs >= -1.0f) && (xs <= (float)HW);
                float x = fminf(fmaxf(xs, 0.0f), (float)(HW - 1));
                int x0 = (int)x, x1i = min(x0 + 1, HW - 1);
                float lx = x - (float)x0;
                float w0 = vx ? 0.5f * (1.0f - lx) : 0.0f; // 0.5 = mean over 2 qx
                float w1 = vx ? 0.5f * lx          : 0.0f;
                int s0 = x0 - cb, s1 = x1i - cb;
                #pragma unroll
                for (int i = 0; i < WC; ++i)
                    WX[s][i] += (s0 == i ? w0 : 0.0f) + (s1 == i ? w1 : 0.0f);
            }
        }
    }

    const float* pf = feat + (size_t)((b * C_CH + chunk * CC) * HW2 + rb * HW + cb);
    float* po = out + (size_t)(((m * C_CH + chunk * CC) << (2 * pSh)) + (py << pSh) + px0);

    #pragma unroll 2
    for (int c = 0; c < CC; ++c) {
        float acc[S];
        #pragma unroll
        for (int s = 0; s < S; ++s) acc[s] = 0.0f;

        // Row-streaming: load one row (vectorized), accumulate, discard.
        #pragma unroll
        for (int j = 0; j < RC; ++j) {
            float f[WC];
            vfloat4 r4 = *(const vfloat4_u*)(pf + j * HW);
            f[0] = r4.x; f[1] = r4.y; f[2] = r4.z; f[3] = r4.w;
            if constexpr (WC == 5) {
                f[4] = pf[j * HW + 4];
            } else if constexpr (WC == 6) {
                F2 t = *(const F2*)(pf + j * HW + 4);
                f[4] = t.x; f[5] = t.y;
            }
            #pragma unroll
            for (int s = 0; s < S; ++s) {
                float rs = 0.0f;
                #pragma unroll
                for (int i = 0; i < WC; ++i) rs += WX[s][i] * f[i];
                acc[s] += WY[j] * rs;
            }
        }

        if constexpr (S == 2) {                    // px0 even -> 8B aligned
            vfloat2 v = {acc[0], acc[1]};
            __builtin_nontemporal_store(v, (vfloat2*)po);
        } else {
            #pragma unroll
            for (int s = 0; s < S; s += 4) {       // px0 mult of 4 -> 16B aligned
                vfloat4 v = {acc[s], acc[s+1], acc[s+2], acc[s+3]};
                __builtin_nontemporal_store(v, (vfloat4*)(po + s));
            }
        }
        pf += HW2;
        po += K;
    }
}

__global__ __launch_bounds__(256, 4) void msroi_kernel(Params p, float* __restrict__ out)
{
    const int blockStart = blockIdx.x * 256;      // blocks never straddle levels
    const int lvl = (blockStart >= p.workBase[1])
                  + (blockStart >= p.workBase[2])
                  + (blockStart >= p.workBase[3]);
    const int r = blockStart + (int)threadIdx.x - p.workBase[lvl];
    // kernel work order (heavy-first): 0->L0 pixels(CC=8), 1->L1 strips(S=2,CC=16),
    //                                  2->L2 strips(S=4,CC=16), 3->L3 strips(S=4,CC=16)
    if (lvl == 0)
        pixel_body<2, 7, 8>(p.feat[0], p.boxes, out + p.outBase[0], r, p.M, p.scale[0]);
    else if (lvl == 1)
        strip_body<3, 6, 2, 6, 4, 16>(p.feat[1], p.boxes, out + p.outBase[1], r, p.M, p.scale[1]);
    else if (lvl == 2)
        strip_body<4, 5, 4, 5, 3, 16>(p.feat[2], p.boxes, out + p.outBase[2], r, p.M, p.scale[2]);
    else
        strip_body<5, 4, 4, 4, 3, 16>(p.feat[3], p.boxes, out + p.outBase[3], r, p.M, p.scale[3]);
}

extern "C" void kernel_launch(void* const* d_in, const int* in_sizes, int n_in,
                              void* d_out, int out_size, void* d_ws, size_t ws_size,
                              hipStream_t stream) {
    const int M = in_sizes[4] / 5;

    Params p;
    p.feat[0] = (const float*)d_in[0];  // [2,256,128,128]
    p.feat[1] = (const float*)d_in[1];  // [2,256,64,64]
    p.feat[2] = (const float*)d_in[2];  // [2,256,32,32]
    p.feat[3] = (const float*)d_in[3];  // [2,256,16,16]
    p.boxes   = (const float*)d_in[4];
    p.M = M;
    const float scales[4] = {0.125f, 0.0625f, 0.03125f, 0.015625f};
    for (int l = 0; l < 4; ++l) p.scale[l] = scales[l];

    // Output bases in reference return order (L0..L3).
    p.outBase[0] = 0;
    p.outBase[1] = p.outBase[0] + (long long)M * C_CH * 4 * 4;
    p.outBase[2] = p.outBase[1] + (long long)M * C_CH * 8 * 8;
    p.outBase[3] = p.outBase[2] + (long long)M * C_CH * 16 * 16;

    // Work sizes (per-level CC): L0 px CC=8, L1 strips S=2 CC=16,
    // L2 strips S=4 CC=16, L3 strips S=4 CC=16.
    const int work[4] = {
        M * (C_CH / 8)  * (4 * 4),        // L0 pixels
        M * (C_CH / 16) * (8 * 8 / 2),    // L1 strips
        M * (C_CH / 16) * (16 * 16 / 4),  // L2 strips
        M * (C_CH / 16) * (32 * 32 / 4)   // L3 strips
    };
    p.workBase[0] = 0;
    for (int i = 0; i < 4; ++i)
        p.workBase[i + 1] = p.workBase[i] + ((work[i] + 255) & ~255);

    const int blocks = p.workBase[4] / 256;
    msroi_kernel<<<blocks, 256, 0, stream>>>(p, (float*)d_out);
}